// Round 7
// baseline (55.790 us; speedup 1.0000x reference)
//
#include <hip/hip_runtime.h>
#include <hip/hip_bf16.h>

// Policy MLP via split-precision bf16 MFMA (round 7 = round 6 with the
// bit-cast compile fix).
// B=131072, D=32, L=40 hidden + final 32->1 (pseudo-layer 41).
//
// Single-variable change vs round 5: remove ALL inline asm. split2 uses
// __float22bfloat162_rn (compiler-emitted RNE conversion) + bit ops, with
// __builtin_memcpy for the bit view (folds to a register move at -O3).
// Rationale: m240 measured hand-asm v_cvt_pk_bf16_f32 as -37% vs
// compiler-generated conversion -- asm "v" constraints pin registers and
// block scheduling around the 16 asm sites/layer, prime suspect for the
// ~4-6x VALU instruction inflation seen in rounds 3-5.
//
// Structure (unchanged): per wave 32 batch cols x 32 out rows as FOUR
// independent 3-deep mfma_f32_16x16x32_bf16 chains:
//   acc = Whi*xhi (C = fp32 bias) ; += Wlo*xhi ; += Whi*xlo
// k-permutation pi(g,j) = 4g+j (j<4) | 16+4g+(j-4), g=lane>>4, applied to
// both A-tables and B-activations so D's natural layout feeds next layer's
// B slots in-lane (zero cross-lane ops).

#define NB 131072
#define DD 32
#define NL 40
#define WTAB_BYTES ((NL + 1) * 4 * 64 * 16)  // int4 [41][4 part][64 lane]

typedef short bf16x8 __attribute__((ext_vector_type(8)));
typedef float f32x4 __attribute__((ext_vector_type(4)));

union Frag { int4 q; int i[4]; bf16x8 v; };
union BFrag { float4 q; f32x4 v; };

__device__ inline unsigned f2bf(float f) {  // fp32 -> bf16 bits, RNE
  unsigned u = __float_as_uint(f);
  return (u + 0x7fffu + ((u >> 16) & 1u)) >> 16;
}
__device__ inline float bf2f(unsigned s) { return __int_as_float((int)(s << 16)); }

// ---- table build ----------------------------------------------------------
// wtab[l][p][lane]: p=0: W[m][pi] hi, p=1: W[16+m][pi] hi, p=2/3: lo parts.
// btab[l][a][lane]: float4 bias for acc rows {16a + 4g + r}.
__global__ __launch_bounds__(64) void build_tables(
    const float* __restrict__ Wh, const float* __restrict__ bh,
    const float* __restrict__ Wout, const float* __restrict__ bout,
    int4* __restrict__ wtab, float4* __restrict__ btab) {
  const int l = blockIdx.x;      // 0..40 (40 == output layer)
  const int lane = threadIdx.x;  // 0..63
  const int m = lane & 15, g = lane >> 4;
  for (int p = 0; p < 4; ++p) {
    const int row = (p & 1) ? (16 + m) : m;
    const bool lopart = (p >= 2);
    int wds[4];
    for (int w = 0; w < 4; ++w) {
      unsigned wd = 0;
      for (int e = 0; e < 2; ++e) {
        const int j = 2 * w + e;
        const int k = (j < 4) ? (4 * g + j) : (16 + 4 * g + (j - 4));  // pi
        float v;
        if (l < NL) v = Wh[(l * 32 + row) * 32 + k];
        else        v = (row == 0) ? Wout[k] : 0.f;  // final: row0 = W_out
        unsigned hi = f2bf(v);
        unsigned val = lopart ? f2bf(v - bf2f(hi)) : hi;
        wd |= val << (16 * e);
      }
      wds[w] = (int)wd;
    }
    wtab[(l * 4 + p) * 64 + lane] = make_int4(wds[0], wds[1], wds[2], wds[3]);
  }
  for (int a = 0; a < 2; ++a) {
    float bv[4];
    for (int r = 0; r < 4; ++r) {
      const int row = 16 * a + 4 * g + r;
      bv[r] = (l < NL) ? bh[l * 32 + row] : ((row == 0) ? bout[0] : 0.f);
    }
    btab[(l * 2 + a) * 64 + lane] = make_float4(bv[0], bv[1], bv[2], bv[3]);
  }
}

// ---- main kernel ----------------------------------------------------------
// No inline asm: compiler picks the conversion instructions and keeps full
// regalloc/scheduling freedom (m240).
__device__ inline void split2(float a, float b, int& hi, int& lo) {
  __hip_bfloat162 h = __float22bfloat162_rn(make_float2(a, b));
  int hbits;
  __builtin_memcpy(&hbits, &h, 4);
  hi = hbits;
  const float ha = __int_as_float(hbits << 16);               // low half -> f32
  const float hb = __int_as_float(hbits & (int)0xffff0000u);  // high half
  __hip_bfloat162 l2 = __float22bfloat162_rn(make_float2(a - ha, b - hb));
  int lbits;
  __builtin_memcpy(&lbits, &l2, 4);
  lo = lbits;
}

#define MFMA16(A, B, C) __builtin_amdgcn_mfma_f32_16x16x32_bf16((A), (B), (C), 0, 0, 0)

__global__ __launch_bounds__(256, 4) void policy_mfma(
    const float* __restrict__ state, const int4* __restrict__ wtab,
    const float4* __restrict__ btab, float* __restrict__ out) {
  const int lane = threadIdx.x & 63;
  const int wid = (int)((blockIdx.x * blockDim.x + threadIdx.x) >> 6);
  const int n = lane & 15, g = lane >> 4;
  const int bbase = wid * 32;  // 32 batch cols per wave (2 x 16-col tiles)

  // Layer-0 B frags from state, pi layout: slots j<4 <- x[4g+j], j>=4 <- x[16+4g+(j-4)]
  Frag bhi[2], blo[2];
#pragma unroll
  for (int t = 0; t < 2; ++t) {
    const float* xr = state + (size_t)(bbase + 16 * t + n) * DD;
    float4 xa = *(const float4*)(xr + 4 * g);
    float4 xc = *(const float4*)(xr + 16 + 4 * g);
    split2(xa.x, xa.y, bhi[t].i[0], blo[t].i[0]);
    split2(xa.z, xa.w, bhi[t].i[1], blo[t].i[1]);
    split2(xc.x, xc.y, bhi[t].i[2], blo[t].i[2]);
    split2(xc.z, xc.w, bhi[t].i[3], blo[t].i[3]);
  }

  // prefetch layer-0 fragments (uniform stride advance)
  const int4* wp = wtab + lane;
  const float4* bp = btab + lane;
  int4 nw0h = wp[0], nw1h = wp[64], nw0l = wp[128], nw1l = wp[192];
  float4 nb0 = bp[0], nb1 = bp[64];

  float res0 = 0.f, res1 = 0.f;

#pragma unroll 1
  for (int l = 0; l <= NL; ++l) {
    Frag w0h, w1h, w0l, w1l;
    w0h.q = nw0h; w1h.q = nw1h; w0l.q = nw0l; w1l.q = nw1l;
    BFrag c0, c1;
    c0.q = nb0; c1.q = nb1;
    if (l < NL) {  // prefetch next layer
      wp += 256; bp += 128;
      nw0h = wp[0]; nw1h = wp[64]; nw0l = wp[128]; nw1l = wp[192];
      nb0 = bp[0]; nb1 = bp[64];
    }

    // 4 independent 3-deep chains (a00/a01 = tile0 rows 0-15/16-31, a1x = tile1)
    f32x4 a00 = MFMA16(w0h.v, bhi[0].v, c0.v);
    f32x4 a01 = MFMA16(w1h.v, bhi[0].v, c1.v);
    f32x4 a10 = MFMA16(w0h.v, bhi[1].v, c0.v);
    f32x4 a11 = MFMA16(w1h.v, bhi[1].v, c1.v);
    a00 = MFMA16(w0l.v, bhi[0].v, a00);
    a01 = MFMA16(w1l.v, bhi[0].v, a01);
    a10 = MFMA16(w0l.v, bhi[1].v, a10);
    a11 = MFMA16(w1l.v, bhi[1].v, a11);
    a00 = MFMA16(w0h.v, blo[0].v, a00);
    a01 = MFMA16(w1h.v, blo[0].v, a01);
    a10 = MFMA16(w0h.v, blo[1].v, a10);
    a11 = MFMA16(w1h.v, blo[1].v, a11);

    if (l < NL) {
      // relu + split; D reg r of accX0 -> slot j=r (k=4g+r), accX1 -> slot 4+r
      split2(fmaxf(a00[0], 0.f), fmaxf(a00[1], 0.f), bhi[0].i[0], blo[0].i[0]);
      split2(fmaxf(a00[2], 0.f), fmaxf(a00[3], 0.f), bhi[0].i[1], blo[0].i[1]);
      split2(fmaxf(a01[0], 0.f), fmaxf(a01[1], 0.f), bhi[0].i[2], blo[0].i[2]);
      split2(fmaxf(a01[2], 0.f), fmaxf(a01[3], 0.f), bhi[0].i[3], blo[0].i[3]);
      split2(fmaxf(a10[0], 0.f), fmaxf(a10[1], 0.f), bhi[1].i[0], blo[1].i[0]);
      split2(fmaxf(a10[2], 0.f), fmaxf(a10[3], 0.f), bhi[1].i[1], blo[1].i[1]);
      split2(fmaxf(a11[0], 0.f), fmaxf(a11[1], 0.f), bhi[1].i[2], blo[1].i[2]);
      split2(fmaxf(a11[2], 0.f), fmaxf(a11[3], 0.f), bhi[1].i[3], blo[1].i[3]);
    } else {
      res0 = a00[0];  // row 0 lives in reg 0 of lanes g==0 (lane<16)
      res1 = a10[0];
    }
  }

  if (lane < 16) {
    out[bbase + n] = res0;
    out[bbase + 16 + n] = res1;
  }
}

extern "C" void kernel_launch(void* const* d_in, const int* in_sizes, int n_in,
                              void* d_out, int out_size, void* d_ws, size_t ws_size,
                              hipStream_t stream) {
  const float* state = (const float*)d_in[0];
  const float* Wh    = (const float*)d_in[1];
  const float* bh    = (const float*)d_in[2];
  const float* Wout  = (const float*)d_in[3];
  const float* bout  = (const float*)d_in[4];
  float* out = (float*)d_out;

  int4* wtab = (int4*)d_ws;
  float4* btab = (float4*)((char*)d_ws + WTAB_BYTES);

  build_tables<<<NL + 1, 64, 0, stream>>>(Wh, bh, Wout, bout, wtab, btab);

  // 131072 rows / 32 per wave = 4096 waves; 256-thread blocks -> 1024 blocks.
  policy_mfma<<<(NB / 32) * 64 / 256, 256, 0, stream>>>(state, wtab, btab, out);
}

// Round 8
// 52.179 us; speedup vs baseline: 1.0692x; 1.0692x over previous
//
#include <hip/hip_runtime.h>

// Policy MLP via split-precision bf16 MFMA (round 8: truncation split).
// B=131072, D=32, L=40 hidden + final 32->1 (pseudo-layer 41).
//
// Round-8 change vs round 7 (single variable): activation hi/lo split by
// TRUNCATION using v_perm_b32 (1 instr packs two high-halves), not RNE
// conversion (~10 instr each in both the asm and intrinsic versions).
// Valid because hi's rounding error is carried by lo: x = hi + lo holds to
// rel 2^-16 regardless of how hi is rounded. Split site: perm + 2 and +
// 2 sub + perm = 6 VALU (+2 fmax relu), 8 sites/wave-layer => ~64 VALU
// vs ~240 measured in rounds 3-7.
//
// Structure (unchanged from r5/r7): per wave 32 batch cols x 32 out rows as
// FOUR independent 3-deep mfma_f32_16x16x32_bf16 chains:
//   acc = Whi*xhi (C = fp32 bias) ; += Wlo*xhi ; += Whi*xlo
// k-permutation pi(g,j) = 4g+j (j<4) | 16+4g+(j-4), g=lane>>4, applied to
// both A-tables and B-activations so D's natural layout feeds next layer's
// B slots in-lane (zero cross-lane ops). Weight tables stay RNE-split
// (built once; rel err 2^-17).

#define NB 131072
#define DD 32
#define NL 40
#define WTAB_BYTES ((NL + 1) * 4 * 64 * 16)  // int4 [41][4 part][64 lane]

typedef short bf16x8 __attribute__((ext_vector_type(8)));
typedef float f32x4 __attribute__((ext_vector_type(4)));

union Frag { int4 q; int i[4]; bf16x8 v; };
union BFrag { float4 q; f32x4 v; };

__device__ inline unsigned f2bf(float f) {  // fp32 -> bf16 bits, RNE
  unsigned u = __float_as_uint(f);
  return (u + 0x7fffu + ((u >> 16) & 1u)) >> 16;
}
__device__ inline float bf2f(unsigned s) { return __int_as_float((int)(s << 16)); }

// ---- table build ----------------------------------------------------------
// wtab[l][p][lane]: p=0: W[m][pi] hi, p=1: W[16+m][pi] hi, p=2/3: lo parts.
// btab[l][a][lane]: float4 bias for acc rows {16a + 4g + r}.
__global__ __launch_bounds__(64) void build_tables(
    const float* __restrict__ Wh, const float* __restrict__ bh,
    const float* __restrict__ Wout, const float* __restrict__ bout,
    int4* __restrict__ wtab, float4* __restrict__ btab) {
  const int l = blockIdx.x;      // 0..40 (40 == output layer)
  const int lane = threadIdx.x;  // 0..63
  const int m = lane & 15, g = lane >> 4;
  for (int p = 0; p < 4; ++p) {
    const int row = (p & 1) ? (16 + m) : m;
    const bool lopart = (p >= 2);
    int wds[4];
    for (int w = 0; w < 4; ++w) {
      unsigned wd = 0;
      for (int e = 0; e < 2; ++e) {
        const int j = 2 * w + e;
        const int k = (j < 4) ? (4 * g + j) : (16 + 4 * g + (j - 4));  // pi
        float v;
        if (l < NL) v = Wh[(l * 32 + row) * 32 + k];
        else        v = (row == 0) ? Wout[k] : 0.f;  // final: row0 = W_out
        unsigned hi = f2bf(v);
        unsigned val = lopart ? f2bf(v - bf2f(hi)) : hi;
        wd |= val << (16 * e);
      }
      wds[w] = (int)wd;
    }
    wtab[(l * 4 + p) * 64 + lane] = make_int4(wds[0], wds[1], wds[2], wds[3]);
  }
  for (int a = 0; a < 2; ++a) {
    float bv[4];
    for (int r = 0; r < 4; ++r) {
      const int row = 16 * a + 4 * g + r;
      bv[r] = (l < NL) ? bh[l * 32 + row] : ((row == 0) ? bout[0] : 0.f);
    }
    btab[(l * 2 + a) * 64 + lane] = make_float4(bv[0], bv[1], bv[2], bv[3]);
  }
}

// ---- main kernel ----------------------------------------------------------
// Truncation split: hi = packed high-halves of (a,b) via one v_perm_b32;
// lo = packed high-halves of the exact residuals. No RNE, no cvt chain.
__device__ inline void split2(float a, float b, int& hi, int& lo) {
  const unsigned ia = __float_as_uint(a), ib = __float_as_uint(b);
  // result bytes [3:2] = ib bytes [3:2], [1:0] = ia bytes [3:2]
  hi = (int)__builtin_amdgcn_perm(ia, ib, 0x03020706u);
  const float ha = __int_as_float((int)(ia & 0xffff0000u));
  const float hb = __int_as_float((int)(ib & 0xffff0000u));
  const float la = a - ha, lb = b - hb;  // exact
  lo = (int)__builtin_amdgcn_perm(__float_as_uint(la), __float_as_uint(lb),
                                  0x03020706u);
}

#define MFMA16(A, B, C) __builtin_amdgcn_mfma_f32_16x16x32_bf16((A), (B), (C), 0, 0, 0)

__global__ __launch_bounds__(256, 4) void policy_mfma(
    const float* __restrict__ state, const int4* __restrict__ wtab,
    const float4* __restrict__ btab, float* __restrict__ out) {
  const int lane = threadIdx.x & 63;
  const int wid = (int)((blockIdx.x * blockDim.x + threadIdx.x) >> 6);
  const int n = lane & 15, g = lane >> 4;
  const int bbase = wid * 32;  // 32 batch cols per wave (2 x 16-col tiles)

  // Layer-0 B frags from state, pi layout: slots j<4 <- x[4g+j], j>=4 <- x[16+4g+(j-4)]
  Frag bhi[2], blo[2];
#pragma unroll
  for (int t = 0; t < 2; ++t) {
    const float* xr = state + (size_t)(bbase + 16 * t + n) * DD;
    float4 xa = *(const float4*)(xr + 4 * g);
    float4 xc = *(const float4*)(xr + 16 + 4 * g);
    split2(xa.x, xa.y, bhi[t].i[0], blo[t].i[0]);
    split2(xa.z, xa.w, bhi[t].i[1], blo[t].i[1]);
    split2(xc.x, xc.y, bhi[t].i[2], blo[t].i[2]);
    split2(xc.z, xc.w, bhi[t].i[3], blo[t].i[3]);
  }

  // prefetch layer-0 fragments (uniform stride advance)
  const int4* wp = wtab + lane;
  const float4* bp = btab + lane;
  int4 nw0h = wp[0], nw1h = wp[64], nw0l = wp[128], nw1l = wp[192];
  float4 nb0 = bp[0], nb1 = bp[64];

  float res0 = 0.f, res1 = 0.f;

#pragma unroll 1
  for (int l = 0; l <= NL; ++l) {
    Frag w0h, w1h, w0l, w1l;
    w0h.q = nw0h; w1h.q = nw1h; w0l.q = nw0l; w1l.q = nw1l;
    BFrag c0, c1;
    c0.q = nb0; c1.q = nb1;
    if (l < NL) {  // prefetch next layer
      wp += 256; bp += 128;
      nw0h = wp[0]; nw1h = wp[64]; nw0l = wp[128]; nw1l = wp[192];
      nb0 = bp[0]; nb1 = bp[64];
    }

    // 4 independent 3-deep chains (a00/a01 = tile0 rows 0-15/16-31, a1x = tile1)
    f32x4 a00 = MFMA16(w0h.v, bhi[0].v, c0.v);
    f32x4 a01 = MFMA16(w1h.v, bhi[0].v, c1.v);
    f32x4 a10 = MFMA16(w0h.v, bhi[1].v, c0.v);
    f32x4 a11 = MFMA16(w1h.v, bhi[1].v, c1.v);
    a00 = MFMA16(w0l.v, bhi[0].v, a00);
    a01 = MFMA16(w1l.v, bhi[0].v, a01);
    a10 = MFMA16(w0l.v, bhi[1].v, a10);
    a11 = MFMA16(w1l.v, bhi[1].v, a11);
    a00 = MFMA16(w0h.v, blo[0].v, a00);
    a01 = MFMA16(w1h.v, blo[0].v, a01);
    a10 = MFMA16(w0h.v, blo[1].v, a10);
    a11 = MFMA16(w1h.v, blo[1].v, a11);

    if (l < NL) {
      // relu + trunc-split; D reg r of accX0 -> slot j=r, accX1 -> slot 4+r
      split2(fmaxf(a00[0], 0.f), fmaxf(a00[1], 0.f), bhi[0].i[0], blo[0].i[0]);
      split2(fmaxf(a00[2], 0.f), fmaxf(a00[3], 0.f), bhi[0].i[1], blo[0].i[1]);
      split2(fmaxf(a01[0], 0.f), fmaxf(a01[1], 0.f), bhi[0].i[2], blo[0].i[2]);
      split2(fmaxf(a01[2], 0.f), fmaxf(a01[3], 0.f), bhi[0].i[3], blo[0].i[3]);
      split2(fmaxf(a10[0], 0.f), fmaxf(a10[1], 0.f), bhi[1].i[0], blo[1].i[0]);
      split2(fmaxf(a10[2], 0.f), fmaxf(a10[3], 0.f), bhi[1].i[1], blo[1].i[1]);
      split2(fmaxf(a11[0], 0.f), fmaxf(a11[1], 0.f), bhi[1].i[2], blo[1].i[2]);
      split2(fmaxf(a11[2], 0.f), fmaxf(a11[3], 0.f), bhi[1].i[3], blo[1].i[3]);
    } else {
      res0 = a00[0];  // row 0 lives in reg 0 of lanes g==0 (lane<16)
      res1 = a10[0];
    }
  }

  if (lane < 16) {
    out[bbase + n] = res0;
    out[bbase + 16 + n] = res1;
  }
}

extern "C" void kernel_launch(void* const* d_in, const int* in_sizes, int n_in,
                              void* d_out, int out_size, void* d_ws, size_t ws_size,
                              hipStream_t stream) {
  const float* state = (const float*)d_in[0];
  const float* Wh    = (const float*)d_in[1];
  const float* bh    = (const float*)d_in[2];
  const float* Wout  = (const float*)d_in[3];
  const float* bout  = (const float*)d_in[4];
  float* out = (float*)d_out;

  int4* wtab = (int4*)d_ws;
  float4* btab = (float4*)((char*)d_ws + WTAB_BYTES);

  build_tables<<<NL + 1, 64, 0, stream>>>(Wh, bh, Wout, bout, wtab, btab);

  // 131072 rows / 32 per wave = 4096 waves; 256-thread blocks -> 1024 blocks.
  policy_mfma<<<(NB / 32) * 64 / 256, 256, 0, stream>>>(state, wtab, btab, out);
}

// Round 9
// 48.257 us; speedup vs baseline: 1.1561x; 1.0813x over previous
//
#include <hip/hip_runtime.h>

// Policy MLP via split-precision bf16 MFMA (round 9: FULL UNROLL).
// B=131072, D=32, L=40 hidden + final 32->1.
//
// Round-9 change vs round 8 (single variable): the 41-layer loop is fully
// unrolled and all manual prefetch/double-buffer unions are deleted.
// Rationale: rounds 3-8 all show ~250 VALU instr/wave-layer while source
// contains ~80 -- invariant across three conversion implementations. The
// remaining suspect is the rolled loop's loop-carried state (weight-prefetch
// copy dance, B-frag phis, AGPR spill of the >48-dword live set) generating
// ~185 compiler-emitted copies per iteration. Unrolling makes every value
// single-assignment: no phis, no forced copies, free load scheduling.
//
// Structure otherwise unchanged from r8: per wave 32 batch cols x 32 out rows
// as FOUR independent 3-deep mfma_f32_16x16x32_bf16 chains per layer:
//   acc = Whi*xhi (C = fp32 bias) ; += Wlo*xhi ; += Whi*xlo
// k-permutation pi(g,j) = 4g+j (j<4) | 16+4g+(j-4), g=lane>>4, applied to
// both A-tables and B-activations so D's natural layout feeds next layer's
// B slots in-lane (zero cross-lane ops). Truncation split via v_perm_b32.

#define NB 131072
#define DD 32
#define NL 40
#define WTAB_BYTES ((NL + 1) * 4 * 64 * 16)  // int4 [41][4 part][64 lane]

typedef short bf16x8 __attribute__((ext_vector_type(8)));
typedef float f32x4 __attribute__((ext_vector_type(4)));

union Frag { int4 q; int i[4]; bf16x8 v; };
union BFrag { float4 q; f32x4 v; };

__device__ inline unsigned f2bf(float f) {  // fp32 -> bf16 bits, RNE
  unsigned u = __float_as_uint(f);
  return (u + 0x7fffu + ((u >> 16) & 1u)) >> 16;
}
__device__ inline float bf2f(unsigned s) { return __int_as_float((int)(s << 16)); }

// ---- table build ----------------------------------------------------------
// wtab[l][p][lane]: p=0: W[m][pi] hi, p=1: W[16+m][pi] hi, p=2/3: lo parts.
// btab[l][a][lane]: float4 bias for acc rows {16a + 4g + r}.
__global__ __launch_bounds__(64) void build_tables(
    const float* __restrict__ Wh, const float* __restrict__ bh,
    const float* __restrict__ Wout, const float* __restrict__ bout,
    int4* __restrict__ wtab, float4* __restrict__ btab) {
  const int l = blockIdx.x;      // 0..40 (40 == output layer)
  const int lane = threadIdx.x;  // 0..63
  const int m = lane & 15, g = lane >> 4;
  for (int p = 0; p < 4; ++p) {
    const int row = (p & 1) ? (16 + m) : m;
    const bool lopart = (p >= 2);
    int wds[4];
    for (int w = 0; w < 4; ++w) {
      unsigned wd = 0;
      for (int e = 0; e < 2; ++e) {
        const int j = 2 * w + e;
        const int k = (j < 4) ? (4 * g + j) : (16 + 4 * g + (j - 4));  // pi
        float v;
        if (l < NL) v = Wh[(l * 32 + row) * 32 + k];
        else        v = (row == 0) ? Wout[k] : 0.f;  // final: row0 = W_out
        unsigned hi = f2bf(v);
        unsigned val = lopart ? f2bf(v - bf2f(hi)) : hi;
        wd |= val << (16 * e);
      }
      wds[w] = (int)wd;
    }
    wtab[(l * 4 + p) * 64 + lane] = make_int4(wds[0], wds[1], wds[2], wds[3]);
  }
  for (int a = 0; a < 2; ++a) {
    float bv[4];
    for (int r = 0; r < 4; ++r) {
      const int row = 16 * a + 4 * g + r;
      bv[r] = (l < NL) ? bh[l * 32 + row] : ((row == 0) ? bout[0] : 0.f);
    }
    btab[(l * 2 + a) * 64 + lane] = make_float4(bv[0], bv[1], bv[2], bv[3]);
  }
}

// ---- main kernel ----------------------------------------------------------
// Truncation split: hi = packed high-halves of (a,b) via one v_perm_b32;
// lo = packed high-halves of the exact residuals.
__device__ inline void split2(float a, float b, int& hi, int& lo) {
  const unsigned ia = __float_as_uint(a), ib = __float_as_uint(b);
  hi = (int)__builtin_amdgcn_perm(ia, ib, 0x03020706u);
  const float ha = __int_as_float((int)(ia & 0xffff0000u));
  const float hb = __int_as_float((int)(ib & 0xffff0000u));
  const float la = a - ha, lb = b - hb;  // exact
  lo = (int)__builtin_amdgcn_perm(__float_as_uint(la), __float_as_uint(lb),
                                  0x03020706u);
}

#define MFMA16(A, B, C) __builtin_amdgcn_mfma_f32_16x16x32_bf16((A), (B), (C), 0, 0, 0)

__global__ __launch_bounds__(256, 4) void policy_mfma(
    const float* __restrict__ state, const int4* __restrict__ wtab,
    const float4* __restrict__ btab, float* __restrict__ out) {
  const int lane = threadIdx.x & 63;
  const int wid = (int)((blockIdx.x * blockDim.x + threadIdx.x) >> 6);
  const int n = lane & 15, g = lane >> 4;
  const int bbase = wid * 32;  // 32 batch cols per wave (2 x 16-col tiles)

  // Layer-0 B frags from state, pi layout: slots j<4 <- x[4g+j], j>=4 <- x[16+4g+(j-4)]
  Frag bhi[2], blo[2];
#pragma unroll
  for (int t = 0; t < 2; ++t) {
    const float* xr = state + (size_t)(bbase + 16 * t + n) * DD;
    float4 xa = *(const float4*)(xr + 4 * g);
    float4 xc = *(const float4*)(xr + 16 + 4 * g);
    split2(xa.x, xa.y, bhi[t].i[0], blo[t].i[0]);
    split2(xa.z, xa.w, bhi[t].i[1], blo[t].i[1]);
    split2(xc.x, xc.y, bhi[t].i[2], blo[t].i[2]);
    split2(xc.z, xc.w, bhi[t].i[3], blo[t].i[3]);
  }

  const int4* wp = wtab + lane;    // per-lane base; layer offsets are static
  const float4* bp = btab + lane;

  // ---- 40 hidden layers, fully unrolled ----
#pragma unroll
  for (int l = 0; l < NL; ++l) {
    Frag w0h, w1h, w0l, w1l;
    w0h.q = wp[l * 256 + 0];
    w1h.q = wp[l * 256 + 64];
    w0l.q = wp[l * 256 + 128];
    w1l.q = wp[l * 256 + 192];
    BFrag c0, c1;
    c0.q = bp[l * 128 + 0];
    c1.q = bp[l * 128 + 64];

    f32x4 a00 = MFMA16(w0h.v, bhi[0].v, c0.v);
    f32x4 a01 = MFMA16(w1h.v, bhi[0].v, c1.v);
    f32x4 a10 = MFMA16(w0h.v, bhi[1].v, c0.v);
    f32x4 a11 = MFMA16(w1h.v, bhi[1].v, c1.v);
    a00 = MFMA16(w0l.v, bhi[0].v, a00);
    a01 = MFMA16(w1l.v, bhi[0].v, a01);
    a10 = MFMA16(w0l.v, bhi[1].v, a10);
    a11 = MFMA16(w1l.v, bhi[1].v, a11);
    a00 = MFMA16(w0h.v, blo[0].v, a00);
    a01 = MFMA16(w1h.v, blo[0].v, a01);
    a10 = MFMA16(w0h.v, blo[1].v, a10);
    a11 = MFMA16(w1h.v, blo[1].v, a11);

    // relu + trunc-split; D reg r of accX0 -> slot j=r, accX1 -> slot 4+r
    split2(fmaxf(a00[0], 0.f), fmaxf(a00[1], 0.f), bhi[0].i[0], blo[0].i[0]);
    split2(fmaxf(a00[2], 0.f), fmaxf(a00[3], 0.f), bhi[0].i[1], blo[0].i[1]);
    split2(fmaxf(a01[0], 0.f), fmaxf(a01[1], 0.f), bhi[0].i[2], blo[0].i[2]);
    split2(fmaxf(a01[2], 0.f), fmaxf(a01[3], 0.f), bhi[0].i[3], blo[0].i[3]);
    split2(fmaxf(a10[0], 0.f), fmaxf(a10[1], 0.f), bhi[1].i[0], blo[1].i[0]);
    split2(fmaxf(a10[2], 0.f), fmaxf(a10[3], 0.f), bhi[1].i[1], blo[1].i[1]);
    split2(fmaxf(a11[0], 0.f), fmaxf(a11[1], 0.f), bhi[1].i[2], blo[1].i[2]);
    split2(fmaxf(a11[2], 0.f), fmaxf(a11[3], 0.f), bhi[1].i[3], blo[1].i[3]);
  }

  // ---- final layer (row 0 only lives in a00/a10 reg 0, lanes g==0) ----
  float res0, res1;
  {
    Frag w0h, w0l;
    w0h.q = wp[NL * 256 + 0];
    w0l.q = wp[NL * 256 + 128];
    BFrag c0;
    c0.q = bp[NL * 128 + 0];
    f32x4 a00 = MFMA16(w0h.v, bhi[0].v, c0.v);
    f32x4 a10 = MFMA16(w0h.v, bhi[1].v, c0.v);
    a00 = MFMA16(w0l.v, bhi[0].v, a00);
    a10 = MFMA16(w0l.v, bhi[1].v, a10);
    a00 = MFMA16(w0h.v, blo[0].v, a00);
    a10 = MFMA16(w0h.v, blo[1].v, a10);
    res0 = a00[0];
    res1 = a10[0];
  }

  if (lane < 16) {
    out[bbase + n] = res0;
    out[bbase + 16 + n] = res1;
  }
}

extern "C" void kernel_launch(void* const* d_in, const int* in_sizes, int n_in,
                              void* d_out, int out_size, void* d_ws, size_t ws_size,
                              hipStream_t stream) {
  const float* state = (const float*)d_in[0];
  const float* Wh    = (const float*)d_in[1];
  const float* bh    = (const float*)d_in[2];
  const float* Wout  = (const float*)d_in[3];
  const float* bout  = (const float*)d_in[4];
  float* out = (float*)d_out;

  int4* wtab = (int4*)d_ws;
  float4* btab = (float4*)((char*)d_ws + WTAB_BYTES);

  build_tables<<<NL + 1, 64, 0, stream>>>(Wh, bh, Wout, bout, wtab, btab);

  // 131072 rows / 32 per wave = 4096 waves; 256-thread blocks -> 1024 blocks.
  policy_mfma<<<(NB / 32) * 64 / 256, 256, 0, stream>>>(state, wtab, btab, out);
}

// Round 10
// 44.561 us; speedup vs baseline: 1.2520x; 1.0829x over previous
//
#include <hip/hip_runtime.h>

// Policy MLP via split-precision bf16 MFMA (round 10: weights in LDS).
// B=131072, D=32, L=40 hidden + final 32->1.
//
// Round-10 change vs round 9: weight fragment tables + compact bias table
// are staged into LDS once per block (1 block = 1 CU, 1024 threads, grid
// 256), and the unrolled layer loop reads them with ds_read_b128 at
// base+immediate offsets. Removes per-layer 64-bit global address
// materialization (~20 VALU/layer), L1 pressure (96 KB/CU/layer), and
// ~200-cycle L2 latency on the critical path (LDS ~20 cyc). Layers 38/39 +
// final layer read from global (LDS capacity); bias for ALL layers is
// compact in LDS (41*32 floats, broadcast reads per 16-lane group).
//
// Structure otherwise = round 9: per wave 32 batch cols x 32 out rows as
// FOUR independent 3-deep mfma_f32_16x16x32_bf16 chains per layer:
//   acc = Whi*xhi (C = fp32 bias) ; += Wlo*xhi ; += Whi*xlo
// k-permutation pi(g,j) = 4g+j (j<4) | 16+4g+(j-4), g=lane>>4, on both A
// and B so D's layout feeds next layer's B slots in-lane. Truncation split
// via v_perm_b32.

#define NB 131072
#define DD 32
#define NL 40
#define BIAS_BYTES ((NL + 1) * 32 * 4)          // 5248, compact fp32 bias
#define WTAB_OFF   BIAS_BYTES
#define WTAB_BYTES ((NL + 1) * 4 * 64 * 16)     // 167936
#define LDS_LAYERS 38
#define LDS_BYTES  (BIAS_BYTES + LDS_LAYERS * 4096)  // 160896 <= 163840

typedef short bf16x8 __attribute__((ext_vector_type(8)));
typedef float f32x4 __attribute__((ext_vector_type(4)));

union Frag { int4 q; int i[4]; bf16x8 v; };
union BFrag { float4 q; f32x4 v; };

__device__ inline unsigned f2bf(float f) {  // fp32 -> bf16 bits, RNE
  unsigned u = __float_as_uint(f);
  return (u + 0x7fffu + ((u >> 16) & 1u)) >> 16;
}
__device__ inline float bf2f(unsigned s) { return __int_as_float((int)(s << 16)); }

// ---- table build ----------------------------------------------------------
// d_ws layout: [bias compact 5248 B][wtab 41 layers x 4096 B].
// wtab[l][p][lane]: p=0: W[m][pi] hi, p=1: W[16+m][pi] hi, p=2/3: lo parts.
__global__ __launch_bounds__(64) void build_tables(
    const float* __restrict__ Wh, const float* __restrict__ bh,
    const float* __restrict__ Wout, const float* __restrict__ bout,
    char* __restrict__ ws) {
  const int l = blockIdx.x;      // 0..40 (40 == output layer)
  const int lane = threadIdx.x;  // 0..63
  const int m = lane & 15, g = lane >> 4;
  int4* wtab = (int4*)(ws + WTAB_OFF);
  float* bc = (float*)ws;
  for (int p = 0; p < 4; ++p) {
    const int row = (p & 1) ? (16 + m) : m;
    const bool lopart = (p >= 2);
    int wds[4];
    for (int w = 0; w < 4; ++w) {
      unsigned wd = 0;
      for (int e = 0; e < 2; ++e) {
        const int j = 2 * w + e;
        const int k = (j < 4) ? (4 * g + j) : (16 + 4 * g + (j - 4));  // pi
        float v;
        if (l < NL) v = Wh[(l * 32 + row) * 32 + k];
        else        v = (row == 0) ? Wout[k] : 0.f;  // final: row0 = W_out
        unsigned hi = f2bf(v);
        unsigned val = lopart ? f2bf(v - bf2f(hi)) : hi;
        wd |= val << (16 * e);
      }
      wds[w] = (int)wd;
    }
    wtab[(l * 4 + p) * 64 + lane] = make_int4(wds[0], wds[1], wds[2], wds[3]);
  }
  if (lane < 32) {  // compact bias, one float per output row
    float bv = (l < NL) ? bh[l * 32 + lane] : ((lane == 0) ? bout[0] : 0.f);
    bc[l * 32 + lane] = bv;
  }
}

// ---- main kernel ----------------------------------------------------------
// Truncation split: hi = packed high-halves of (a,b) via one v_perm_b32;
// lo = packed high-halves of the exact residuals.
__device__ inline void split2(float a, float b, int& hi, int& lo) {
  const unsigned ia = __float_as_uint(a), ib = __float_as_uint(b);
  hi = (int)__builtin_amdgcn_perm(ia, ib, 0x03020706u);
  const float ha = __int_as_float((int)(ia & 0xffff0000u));
  const float hb = __int_as_float((int)(ib & 0xffff0000u));
  const float la = a - ha, lb = b - hb;  // exact
  lo = (int)__builtin_amdgcn_perm(__float_as_uint(la), __float_as_uint(lb),
                                  0x03020706u);
}

#define MFMA16(A, B, C) __builtin_amdgcn_mfma_f32_16x16x32_bf16((A), (B), (C), 0, 0, 0)

__global__ __launch_bounds__(1024, 4) void policy_mfma(
    const float* __restrict__ state, const char* __restrict__ tab,
    float* __restrict__ out) {
  extern __shared__ char smem[];
  const int tid = threadIdx.x;
  const int lane = tid & 63;
  const int n = lane & 15, g = lane >> 4;

  // ---- stage tables into LDS (one-time, ~157 KB) ----
  {
    const int4* src = (const int4*)tab;
    int4* dst = (int4*)smem;
    for (int i = tid; i < LDS_BYTES / 16; i += 1024) dst[i] = src[i];
  }

  const int wid = blockIdx.x * 16 + (tid >> 6);
  const int bbase = wid * 32;  // 32 batch cols per wave (2 x 16-col tiles)

  // Layer-0 B frags from state (overlaps with staging; no LDS dependency)
  Frag bhi[2], blo[2];
#pragma unroll
  for (int t = 0; t < 2; ++t) {
    const float* xr = state + (size_t)(bbase + 16 * t + n) * DD;
    float4 xa = *(const float4*)(xr + 4 * g);
    float4 xc = *(const float4*)(xr + 16 + 4 * g);
    split2(xa.x, xa.y, bhi[t].i[0], blo[t].i[0]);
    split2(xa.z, xa.w, bhi[t].i[1], blo[t].i[1]);
    split2(xc.x, xc.y, bhi[t].i[2], blo[t].i[2]);
    split2(xc.z, xc.w, bhi[t].i[3], blo[t].i[3]);
  }

  __syncthreads();  // LDS tables ready

  const int4* lw = (const int4*)(smem + WTAB_OFF);   // LDS weights (l<38)
  const float* lb = (const float*)smem;              // LDS compact bias (all l)
  const int4* gw = (const int4*)(tab + WTAB_OFF);    // global weights (l>=38)

  auto layer = [&](int l, const int4* __restrict__ WP) {
    Frag w0h, w1h, w0l, w1l;
    w0h.q = WP[l * 256 + lane];
    w1h.q = WP[l * 256 + 64 + lane];
    w0l.q = WP[l * 256 + 128 + lane];
    w1l.q = WP[l * 256 + 192 + lane];
    BFrag c0, c1;
    c0.q = *(const float4*)(lb + l * 32 + 4 * g);        // rows 4g..4g+3
    c1.q = *(const float4*)(lb + l * 32 + 16 + 4 * g);   // rows 16+4g..

    f32x4 a00 = MFMA16(w0h.v, bhi[0].v, c0.v);
    f32x4 a01 = MFMA16(w1h.v, bhi[0].v, c1.v);
    f32x4 a10 = MFMA16(w0h.v, bhi[1].v, c0.v);
    f32x4 a11 = MFMA16(w1h.v, bhi[1].v, c1.v);
    a00 = MFMA16(w0l.v, bhi[0].v, a00);
    a01 = MFMA16(w1l.v, bhi[0].v, a01);
    a10 = MFMA16(w0l.v, bhi[1].v, a10);
    a11 = MFMA16(w1l.v, bhi[1].v, a11);
    a00 = MFMA16(w0h.v, blo[0].v, a00);
    a01 = MFMA16(w1h.v, blo[0].v, a01);
    a10 = MFMA16(w0h.v, blo[1].v, a10);
    a11 = MFMA16(w1h.v, blo[1].v, a11);

    // relu + trunc-split; D reg r of accX0 -> slot j=r, accX1 -> slot 4+r
    split2(fmaxf(a00[0], 0.f), fmaxf(a00[1], 0.f), bhi[0].i[0], blo[0].i[0]);
    split2(fmaxf(a00[2], 0.f), fmaxf(a00[3], 0.f), bhi[0].i[1], blo[0].i[1]);
    split2(fmaxf(a01[0], 0.f), fmaxf(a01[1], 0.f), bhi[0].i[2], blo[0].i[2]);
    split2(fmaxf(a01[2], 0.f), fmaxf(a01[3], 0.f), bhi[0].i[3], blo[0].i[3]);
    split2(fmaxf(a10[0], 0.f), fmaxf(a10[1], 0.f), bhi[1].i[0], blo[1].i[0]);
    split2(fmaxf(a10[2], 0.f), fmaxf(a10[3], 0.f), bhi[1].i[1], blo[1].i[1]);
    split2(fmaxf(a11[0], 0.f), fmaxf(a11[1], 0.f), bhi[1].i[2], blo[1].i[2]);
    split2(fmaxf(a11[2], 0.f), fmaxf(a11[3], 0.f), bhi[1].i[3], blo[1].i[3]);
  };

#pragma unroll
  for (int l = 0; l < LDS_LAYERS; ++l) layer(l, lw);   // LDS path
#pragma unroll
  for (int l = LDS_LAYERS; l < NL; ++l) layer(l, gw);  // global tail

  // ---- final layer (rows 16-31 of W are zero; only w0h/w0l needed) ----
  float res0, res1;
  {
    Frag w0h, w0l;
    w0h.q = gw[NL * 256 + lane];
    w0l.q = gw[NL * 256 + 128 + lane];
    BFrag c0;
    c0.q = *(const float4*)(lb + NL * 32 + 4 * g);
    f32x4 a00 = MFMA16(w0h.v, bhi[0].v, c0.v);
    f32x4 a10 = MFMA16(w0h.v, bhi[1].v, c0.v);
    a00 = MFMA16(w0l.v, bhi[0].v, a00);
    a10 = MFMA16(w0l.v, bhi[1].v, a10);
    a00 = MFMA16(w0h.v, blo[0].v, a00);
    a10 = MFMA16(w0h.v, blo[1].v, a10);
    res0 = a00[0];  // row 0 lives in reg 0 of lanes g==0
    res1 = a10[0];
  }

  if (lane < 16) {
    out[bbase + n] = res0;
    out[bbase + 16 + n] = res1;
  }
}

extern "C" void kernel_launch(void* const* d_in, const int* in_sizes, int n_in,
                              void* d_out, int out_size, void* d_ws, size_t ws_size,
                              hipStream_t stream) {
  const float* state = (const float*)d_in[0];
  const float* Wh    = (const float*)d_in[1];
  const float* bh    = (const float*)d_in[2];
  const float* Wout  = (const float*)d_in[3];
  const float* bout  = (const float*)d_in[4];
  float* out = (float*)d_out;

  build_tables<<<NL + 1, 64, 0, stream>>>(Wh, bh, Wout, bout, (char*)d_ws);

  // 4096 waves total; 16 waves (1024 threads) per block; 256 blocks = 1/CU.
  policy_mfma<<<256, 1024, LDS_BYTES, stream>>>(state, (const char*)d_ws, out);
}